// Round 12
// baseline (735.561 us; speedup 1.0000x reference)
//
#include <hip/hip_runtime.h>
#include <hip/hip_bf16.h>
#include <hip/hip_fp16.h>

#define NN    50000
#define NE    800000
#define INF   3
#define EMB   16
#define EDGEF 6
#define KW    128
#define OUTK  256   // EMB*EMB
#define NCONV 4

typedef unsigned int  u32;
typedef unsigned short u16;
typedef __attribute__((ext_vector_type(8))) _Float16 f16x8;
typedef __attribute__((ext_vector_type(4))) float f32x4;

union B128 { uint4 u; f16x8 h; };
union H16  { u16 u; _Float16 h; };

__device__ __forceinline__ u16 f2h(float f) {
    union { _Float16 h; u16 u; } v; v.h = (_Float16)f;   // v_cvt_f16_f32, RNE
    return v.u;
}

// ---------------- node embedding ----------------
__global__ void embed_k(const float* __restrict__ x, const float* __restrict__ w,
                        const float* __restrict__ b, float* __restrict__ h) {
    int idx = blockIdx.x * blockDim.x + threadIdx.x;
    if (idx >= NN * EMB) return;
    int n = idx >> 4, o = idx & 15;
    float acc = b[o];
#pragma unroll
    for (int i = 0; i < INF; ++i) acc += x[n * INF + i] * w[i * EMB + o];
    h[idx] = acc;
}

// ---------------- in-degree counts ----------------
__global__ void count_k(const int* __restrict__ dst, float* __restrict__ counts) {
    int e = blockIdx.x * blockDim.x + threadIdx.x;
    if (e >= NE) return;
    atomicAdd(&counts[dst[e]], 1.0f);
}

// ---------------- weight prep: pack w1/w2/w3 into per-lane MFMA B-fragment order ----
// k-slot bijection (shared by A-pack and B-prep):
//   stage1 (no pairing):  k = (lane>>4)*8 + j          (k<6 real, else 0)
//   stage2/3 (paired):    k = ks*32 + (lane>>4)*4 + (j>>1) + 16*(j&1)
__global__ void prep_k(const float* __restrict__ w1, const float* __restrict__ w2,
                       const float* __restrict__ w3,
                       u16* __restrict__ w1p, u16* __restrict__ w2p, u16* __restrict__ w3p)
{
    int idx = blockIdx.x * 256 + threadIdx.x;
    if (idx < 4096) {                       // w1p [nt=8][lane=64][j=8]
        int j = idx & 7, l = (idx >> 3) & 63, nt = idx >> 9;
        int kk = (l >> 4) * 8 + j;
        int col = nt * 16 + (l & 15);
        w1p[idx] = (kk < EDGEF) ? f2h(w1[kk * KW + col]) : (u16)0;
    } else if (idx < 20480) {               // w2p [nt=8][ks=4][lane=64][j=8]
        int i2 = idx - 4096;
        int j = i2 & 7, l = (i2 >> 3) & 63, ks = (i2 >> 9) & 3, nt = i2 >> 11;
        int kk = ks * 32 + ((l >> 4) * 4) + (j >> 1) + 16 * (j & 1);
        int col = nt * 16 + (l & 15);
        w2p[i2] = f2h(w2[kk * KW + col]);
    } else if (idx < 53248) {               // w3p [ct=16][ks=4][lane=64][j=8]
        int i3 = idx - 20480;
        int j = i3 & 7, l = (i3 >> 3) & 63, ks = (i3 >> 9) & 3, ct = i3 >> 11;
        int kk = ks * 32 + ((l >> 4) * 4) + (j >> 1) + 16 * (j & 1);
        int col = ct * 16 + (l & 15);
        w3p[i3] = f2h(w3[kk * OUTK + col]);
    }
}

// ---------------- fused MFMA conv kernel: EXACT r7 structure (proven no-spill) ----
// 64 edges/block, 128 threads = 2 waves; each wave owns 32 edges = 2 M-tiles.
// STORE_A3: additionally write the stage-3 A-fragments (== e2 in frag layout) to
// a3c for reuse in later conv iterations (they depend only on edge_attr).
template <int STORE_A3>
__device__ __forceinline__ void gno_body(
    const int* __restrict__ ei, const float* __restrict__ ea,
    const uint4* __restrict__ w1p, const float* __restrict__ b1,
    const uint4* __restrict__ w2p, const float* __restrict__ b2,
    const uint4* __restrict__ w3p, const float* __restrict__ b3,
    const float* __restrict__ h, float* __restrict__ agg,
    uint4* __restrict__ a3c)
{
    __shared__ u16   eas[64 * EDGEF];     // fp16 edge attrs
    __shared__ int   dids[64];
    __shared__ float hsst[16 * 64];       // transposed gather: hsst[i][edge]
    __shared__ u32   e12[2 * 32 * 64];    // per-wave act buffer (XOR-swizzled)

    const int t  = threadIdx.x;
    const long e0 = (long)blockIdx.x * 64;

    for (int k = t; k < 64 * EDGEF; k += 128) eas[k] = f2h(ea[e0 * EDGEF + k]);
    if (t < 64) dids[t] = ei[NE + e0 + t];
    {
        int edge = t >> 1, i0 = (t & 1) * 8;
        int sid = ei[e0 + edge];
        f32x4 v0 = *(const f32x4*)&h[(long)sid * EMB + i0];
        f32x4 v1 = *(const f32x4*)&h[(long)sid * EMB + i0 + 4];
#pragma unroll
        for (int j = 0; j < 4; ++j) {
            hsst[(i0 + j) * 64 + edge]     = v0[j];
            hsst[(i0 + 4 + j) * 64 + edge] = v1[j];
        }
    }
    __syncthreads();   // the ONLY barrier: eas/dids/hsst read-only below

    const int wid = t >> 6, lane = t & 63, o = lane & 15, g = lane >> 4;
    u32* eb = &e12[wid * 2048];

    // ---- stage 1: A-frag from ea (k = g*8+j, real k<6) ----
    f16x8 a1[2];
#pragma unroll
    for (int m = 0; m < 2; ++m) {
        f16x8 a = {0, 0, 0, 0, 0, 0, 0, 0};
        if (g == 0) {
#pragma unroll
            for (int j = 0; j < EDGEF; ++j) {
                H16 v; v.u = eas[(wid * 32 + m * 16 + o) * EDGEF + j];
                a[j] = v.h;
            }
        }
        a1[m] = a;
    }
#pragma unroll
    for (int p = 0; p < 4; ++p) {
        f32x4 acc[2][2] = {};
#pragma unroll
        for (int nth = 0; nth < 2; ++nth) {
            B128 bb; bb.u = w1p[(p * 2 + nth) * 64 + lane];
#pragma unroll
            for (int m = 0; m < 2; ++m)
                acc[m][nth] = __builtin_amdgcn_mfma_f32_16x16x32_f16(a1[m], bb.h, acc[m][nth], 0, 0, 0);
        }
        float blo = b1[(p * 2) * 16 + o], bhi = b1[(p * 2 + 1) * 16 + o];
#pragma unroll
        for (int m = 0; m < 2; ++m)
#pragma unroll
            for (int r = 0; r < 4; ++r) {
                float lo = fmaxf(acc[m][0][r] + blo, 0.f);
                float hi = fmaxf(acc[m][1][r] + bhi, 0.f);
                int el = m * 16 + g * 4 + r;
                eb[(el * 64 + p * 16 + o) ^ ((el & 7) << 2)] =
                    (u32)f2h(lo) | ((u32)f2h(hi) << 16);
            }
    }
    // no barrier: eb is wave-private, DS ops in-order within a wave

    // ---- stage 2: e1 @ w2 ----
    f16x8 a2[2][4];
#pragma unroll
    for (int m = 0; m < 2; ++m) {
        int el = m * 16 + o;
#pragma unroll
        for (int ks = 0; ks < 4; ++ks) {
            B128 v; v.u = *(const uint4*)&eb[(el * 64 + ks * 16 + g * 4) ^ ((el & 7) << 2)];
            a2[m][ks] = v.h;
        }
    }
#pragma unroll
    for (int p = 0; p < 4; ++p) {
        f32x4 acc[2][2] = {};
#pragma unroll
        for (int ks = 0; ks < 4; ++ks)
#pragma unroll
            for (int nth = 0; nth < 2; ++nth) {
                B128 bb; bb.u = w2p[((p * 2 + nth) * 4 + ks) * 64 + lane];
#pragma unroll
                for (int m = 0; m < 2; ++m)
                    acc[m][nth] = __builtin_amdgcn_mfma_f32_16x16x32_f16(a2[m][ks], bb.h, acc[m][nth], 0, 0, 0);
            }
        float blo = b2[(p * 2) * 16 + o], bhi = b2[(p * 2 + 1) * 16 + o];
#pragma unroll
        for (int m = 0; m < 2; ++m)
#pragma unroll
            for (int r = 0; r < 4; ++r) {
                float lo = fmaxf(acc[m][0][r] + blo, 0.f);
                float hi = fmaxf(acc[m][1][r] + bhi, 0.f);
                int el = m * 16 + g * 4 + r;
                eb[(el * 64 + p * 16 + o) ^ ((el & 7) << 2)] =
                    (u32)f2h(lo) | ((u32)f2h(hi) << 16);
            }
    }

    // ---- stage 3: e2 @ w3, fold msg, scatter ----
    f16x8 a3[2][4];
#pragma unroll
    for (int m = 0; m < 2; ++m) {
        int el = m * 16 + o;
#pragma unroll
        for (int ks = 0; ks < 4; ++ks) {
            B128 v; v.u = *(const uint4*)&eb[(el * 64 + ks * 16 + g * 4) ^ ((el & 7) << 2)];
            a3[m][ks] = v.h;
        }
    }
    if (STORE_A3) {
        const long tb = ((long)blockIdx.x * 4 + wid * 2) * 4;   // tile*4ks base
#pragma unroll
        for (int m = 0; m < 2; ++m)
#pragma unroll
            for (int ks = 0; ks < 4; ++ks) {
                B128 v; v.h = a3[m][ks];
                a3c[(tb + m * 4 + ks) * 64 + lane] = v.u;
            }
    }
    f32x4 msg[2] = {};
#pragma unroll
    for (int ct = 0; ct < 16; ++ct) {
        f32x4 acc[2] = {};
#pragma unroll
        for (int ks = 0; ks < 4; ++ks) {
            B128 bb; bb.u = w3p[(ct * 4 + ks) * 64 + lane];
#pragma unroll
            for (int m = 0; m < 2; ++m)
                acc[m] = __builtin_amdgcn_mfma_f32_16x16x32_f16(a3[m][ks], bb.h, acc[m], 0, 0, 0);
        }
        float b3v = b3[ct * 16 + o];
#pragma unroll
        for (int m = 0; m < 2; ++m) {
            f32x4 hv = *(const f32x4*)&hsst[ct * 64 + wid * 32 + m * 16 + g * 4];
#pragma unroll
            for (int r = 0; r < 4; ++r)
                msg[m][r] += (acc[m][r] + b3v) * hv[r];
        }
    }
#pragma unroll
    for (int m = 0; m < 2; ++m)
#pragma unroll
        for (int r = 0; r < 4; ++r) {
            int elb = wid * 32 + m * 16 + g * 4 + r;
            atomicAdd(&agg[(long)dids[elb] * EMB + o], msg[m][r]);
        }
}

__global__ __launch_bounds__(128, 4) void gno_k(
    const int* __restrict__ ei, const float* __restrict__ ea,
    const uint4* __restrict__ w1p, const float* __restrict__ b1,
    const uint4* __restrict__ w2p, const float* __restrict__ b2,
    const uint4* __restrict__ w3p, const float* __restrict__ b3,
    const float* __restrict__ h, float* __restrict__ agg)
{
    gno_body<0>(ei, ea, w1p, b1, w2p, b2, w3p, b3, h, agg, nullptr);
}

__global__ __launch_bounds__(128, 4) void gno_store_k(
    const int* __restrict__ ei, const float* __restrict__ ea,
    const uint4* __restrict__ w1p, const float* __restrict__ b1,
    const uint4* __restrict__ w2p, const float* __restrict__ b2,
    const uint4* __restrict__ w3p, const float* __restrict__ b3,
    const float* __restrict__ h, float* __restrict__ agg,
    uint4* __restrict__ a3c)
{
    gno_body<1>(ei, ea, w1p, b1, w2p, b2, w3p, b3, h, agg, a3c);
}

// ---------------- reuse kernel: stage 3 only, a3 frags from cache ----------------
// R12: 1 wave (64 threads) per block, 4 M-tiles (64 edges) per wave:
//  - each w3p fragment load feeds 4 independent MFMA chains (4x ILP per ct step)
//  - w3p L2 traffic per dispatch halves (12500 waves x 64 KB vs 25000 x 64 KB)
//  - per-wave fixed tails (a3c loads, atomics) amortized over 2x edges.
// launch_bounds(64) with NO min-waves arg: allocator free up to 256 VGPR
// (a3[4][4]=64 + msg 16 + acc 16 + misc ~= 120; r8/r9 spills came from
// constrained budgets -- do not constrain here).
__global__ __launch_bounds__(64) void gno_reuse_k(
    const int* __restrict__ ei, const uint4* __restrict__ a3c,
    const uint4* __restrict__ w3p, const float* __restrict__ b3,
    const float* __restrict__ h, float* __restrict__ agg)
{
    __shared__ int   dids[64];
    __shared__ float hsst[16 * 64];

    const int t  = threadIdx.x;           // == lane, 0..63
    const long e0 = (long)blockIdx.x * 64;

    dids[t] = ei[NE + e0 + t];
    {
        int sid = ei[e0 + t];
#pragma unroll
        for (int q = 0; q < 4; ++q) {
            f32x4 v = *(const f32x4*)&h[(long)sid * EMB + q * 4];
#pragma unroll
            for (int j = 0; j < 4; ++j)
                hsst[(q * 4 + j) * 64 + t] = v[j];
        }
    }
    __syncthreads();

    const int lane = t, o = lane & 15, g = lane >> 4;

    f16x8 a3[4][4];
    const long tb = (long)blockIdx.x * 16;        // 4 tiles x 4 ks
#pragma unroll
    for (int m = 0; m < 4; ++m)
#pragma unroll
        for (int ks = 0; ks < 4; ++ks) {
            B128 v; v.u = a3c[(tb + m * 4 + ks) * 64 + lane];
            a3[m][ks] = v.h;
        }

    f32x4 msg[4] = {};
#pragma unroll
    for (int ct = 0; ct < 16; ++ct) {
        f32x4 acc[4] = {};
#pragma unroll
        for (int ks = 0; ks < 4; ++ks) {
            B128 bb; bb.u = w3p[(ct * 4 + ks) * 64 + lane];
#pragma unroll
            for (int m = 0; m < 4; ++m)
                acc[m] = __builtin_amdgcn_mfma_f32_16x16x32_f16(a3[m][ks], bb.h, acc[m], 0, 0, 0);
        }
        float b3v = b3[ct * 16 + o];
#pragma unroll
        for (int m = 0; m < 4; ++m) {
            f32x4 hv = *(const f32x4*)&hsst[ct * 64 + m * 16 + g * 4];
#pragma unroll
            for (int r = 0; r < 4; ++r)
                msg[m][r] += (acc[m][r] + b3v) * hv[r];
        }
    }
#pragma unroll
    for (int m = 0; m < 4; ++m)
#pragma unroll
        for (int r = 0; r < 4; ++r) {
            int elb = m * 16 + g * 4 + r;
            atomicAdd(&agg[(long)dids[elb] * EMB + o], msg[m][r]);
        }
}

// ---------------- node update ----------------
__global__ void update_k(const float* __restrict__ agg, const float* __restrict__ counts,
        const float* __restrict__ h, const float* __restrict__ rw,
        const float* __restrict__ cb, float* __restrict__ hn)
{
    int idx = blockIdx.x * blockDim.x + threadIdx.x;
    if (idx >= NN * EMB) return;
    int n = idx >> 4, o = idx & 15;
    float acc = cb[o];
#pragma unroll
    for (int i = 0; i < EMB; ++i) acc += h[n * EMB + i] * rw[i * EMB + o];
    float a = agg[idx] / fmaxf(counts[n], 1.0f);
    hn[idx] = fmaxf(acc + a, 0.0f);
}

// ---------------- inverse embedding ----------------
__global__ void final_k(const float* __restrict__ h, const float* __restrict__ iw,
        const float* __restrict__ ib, float* __restrict__ out)
{
    int idx = blockIdx.x * blockDim.x + threadIdx.x;
    if (idx >= NN * INF) return;
    int n = idx / INF, f = idx % INF;
    float acc = ib[f];
#pragma unroll
    for (int i = 0; i < EMB; ++i) acc += h[n * EMB + i] * iw[i * INF + f];
    out[idx] = acc;
}

extern "C" void kernel_launch(void* const* d_in, const int* in_sizes, int n_in,
                              void* d_out, int out_size, void* d_ws, size_t ws_size,
                              hipStream_t stream)
{
    const float* x     = (const float*)d_in[0];
    const int*   ei    = (const int*)d_in[1];
    const float* ea    = (const float*)d_in[2];
    const float* emb_w = (const float*)d_in[3];
    const float* emb_b = (const float*)d_in[4];
    const float* k1w   = (const float*)d_in[5];
    const float* k1b   = (const float*)d_in[6];
    const float* k2w   = (const float*)d_in[7];
    const float* k2b   = (const float*)d_in[8];
    const float* k3w   = (const float*)d_in[9];
    const float* k3b   = (const float*)d_in[10];
    const float* rw    = (const float*)d_in[11];
    const float* cb    = (const float*)d_in[12];
    const float* iw    = (const float*)d_in[13];
    const float* ib    = (const float*)d_in[14];
    float* out = (float*)d_out;

    char* ws = (char*)d_ws;
    u16* w1p = (u16*)(ws);                    //  8 KB  (4096)
    u16* w2p = (u16*)(ws + 8192);             // 32 KB  (16384)
    u16* w3p = (u16*)(ws + 40960);            // 64 KB  (32768)
    size_t off = 106496;                      // 256B-aligned
    float* h0     = (float*)(ws + off); off += (size_t)NN * EMB * sizeof(float);
    float* h1     = (float*)(ws + off); off += (size_t)NN * EMB * sizeof(float);
    float* agg    = (float*)(ws + off); off += (size_t)NN * EMB * sizeof(float);
    float* counts = (float*)(ws + off); off += (size_t)NN * sizeof(float);

    // a3 fragment cache: 50000 tiles x 4 ks x 64 lanes x 16 B = 204.8 MB
    off = (off + 255) & ~(size_t)255;
    uint4* a3c = (uint4*)(ws + off);
    const size_t A3_BYTES = (size_t)(NE / 16) * 4 * 64 * 16;
    const bool cacheA3 = (ws_size >= off + A3_BYTES);

    hipMemsetAsync(counts, 0, (size_t)NN * sizeof(float), stream);
    prep_k<<<208, 256, 0, stream>>>(k1w, k2w, k3w, w1p, w2p, w3p);
    embed_k<<<(NN * EMB + 255) / 256, 256, 0, stream>>>(x, emb_w, emb_b, h0);
    count_k<<<(NE + 255) / 256, 256, 0, stream>>>(ei + NE, counts);

    float* hc = h0;
    float* hn = h1;
    for (int it = 0; it < NCONV; ++it) {
        hipMemsetAsync(agg, 0, (size_t)NN * EMB * sizeof(float), stream);
        if (!cacheA3) {
            gno_k<<<NE / 64, 128, 0, stream>>>(ei, ea,
                    (const uint4*)w1p, k1b, (const uint4*)w2p, k2b,
                    (const uint4*)w3p, k3b, hc, agg);
        } else if (it == 0) {
            gno_store_k<<<NE / 64, 128, 0, stream>>>(ei, ea,
                    (const uint4*)w1p, k1b, (const uint4*)w2p, k2b,
                    (const uint4*)w3p, k3b, hc, agg, a3c);
        } else {
            gno_reuse_k<<<NE / 64, 64, 0, stream>>>(ei, a3c,
                    (const uint4*)w3p, k3b, hc, agg);
        }
        update_k<<<(NN * EMB + 255) / 256, 256, 0, stream>>>(agg, counts, hc, rw, cb, hn);
        float* tmp = hc; hc = hn; hn = tmp;
    }
    final_k<<<(NN * INF + 255) / 256, 256, 0, stream>>>(hc, iw, ib, out);
}

// Round 13
// 655.886 us; speedup vs baseline: 1.1215x; 1.1215x over previous
//
#include <hip/hip_runtime.h>
#include <hip/hip_bf16.h>
#include <hip/hip_fp16.h>

#define NN    50000
#define NE    800000
#define INF   3
#define EMB   16
#define EDGEF 6
#define KW    128
#define OUTK  256   // EMB*EMB
#define NCONV 4

typedef unsigned int  u32;
typedef unsigned short u16;
typedef __attribute__((ext_vector_type(8))) _Float16 f16x8;
typedef __attribute__((ext_vector_type(4))) float f32x4;

union B128 { uint4 u; f16x8 h; };
union H16  { u16 u; _Float16 h; };

__device__ __forceinline__ u16 f2h(float f) {
    union { _Float16 h; u16 u; } v; v.h = (_Float16)f;   // v_cvt_f16_f32, RNE
    return v.u;
}

// ---------------- node embedding ----------------
__global__ void embed_k(const float* __restrict__ x, const float* __restrict__ w,
                        const float* __restrict__ b, float* __restrict__ h) {
    int idx = blockIdx.x * blockDim.x + threadIdx.x;
    if (idx >= NN * EMB) return;
    int n = idx >> 4, o = idx & 15;
    float acc = b[o];
#pragma unroll
    for (int i = 0; i < INF; ++i) acc += x[n * INF + i] * w[i * EMB + o];
    h[idx] = acc;
}

// ---------------- in-degree counts ----------------
__global__ void count_k(const int* __restrict__ dst, float* __restrict__ counts) {
    int e = blockIdx.x * blockDim.x + threadIdx.x;
    if (e >= NE) return;
    atomicAdd(&counts[dst[e]], 1.0f);
}

// ---------------- weight prep: pack w1/w2/w3 into per-lane MFMA B-fragment order ----
// k-slot bijection (shared by A-pack and B-prep):
//   stage1 (no pairing):  k = (lane>>4)*8 + j          (k<6 real, else 0)
//   stage2/3 (paired):    k = ks*32 + (lane>>4)*4 + (j>>1) + 16*(j&1)
__global__ void prep_k(const float* __restrict__ w1, const float* __restrict__ w2,
                       const float* __restrict__ w3,
                       u16* __restrict__ w1p, u16* __restrict__ w2p, u16* __restrict__ w3p)
{
    int idx = blockIdx.x * 256 + threadIdx.x;
    if (idx < 4096) {                       // w1p [nt=8][lane=64][j=8]
        int j = idx & 7, l = (idx >> 3) & 63, nt = idx >> 9;
        int kk = (l >> 4) * 8 + j;
        int col = nt * 16 + (l & 15);
        w1p[idx] = (kk < EDGEF) ? f2h(w1[kk * KW + col]) : (u16)0;
    } else if (idx < 20480) {               // w2p [nt=8][ks=4][lane=64][j=8]
        int i2 = idx - 4096;
        int j = i2 & 7, l = (i2 >> 3) & 63, ks = (i2 >> 9) & 3, nt = i2 >> 11;
        int kk = ks * 32 + ((l >> 4) * 4) + (j >> 1) + 16 * (j & 1);
        int col = nt * 16 + (l & 15);
        w2p[i2] = f2h(w2[kk * KW + col]);
    } else if (idx < 53248) {               // w3p [ct=16][ks=4][lane=64][j=8]
        int i3 = idx - 20480;
        int j = i3 & 7, l = (i3 >> 3) & 63, ks = (i3 >> 9) & 3, ct = i3 >> 11;
        int kk = ks * 32 + ((l >> 4) * 4) + (j >> 1) + 16 * (j & 1);
        int col = ct * 16 + (l & 15);
        w3p[i3] = f2h(w3[kk * OUTK + col]);
    }
}

// ---------------- fused MFMA conv kernel: EXACT r7 structure (proven no-spill) ----
// 64 edges/block, 128 threads = 2 waves; each wave owns 32 edges = 2 M-tiles.
// STORE_A3: additionally write the stage-3 A-fragments (== e2 in frag layout) to
// a3c for reuse in later conv iterations (they depend only on edge_attr).
template <int STORE_A3>
__device__ __forceinline__ void gno_body(
    const int* __restrict__ ei, const float* __restrict__ ea,
    const uint4* __restrict__ w1p, const float* __restrict__ b1,
    const uint4* __restrict__ w2p, const float* __restrict__ b2,
    const uint4* __restrict__ w3p, const float* __restrict__ b3,
    const float* __restrict__ h, float* __restrict__ agg,
    uint4* __restrict__ a3c)
{
    __shared__ u16   eas[64 * EDGEF];     // fp16 edge attrs
    __shared__ int   dids[64];
    __shared__ float hsst[16 * 64];       // transposed gather: hsst[i][edge]
    __shared__ u32   e12[2 * 32 * 64];    // per-wave act buffer (XOR-swizzled)

    const int t  = threadIdx.x;
    const long e0 = (long)blockIdx.x * 64;

    for (int k = t; k < 64 * EDGEF; k += 128) eas[k] = f2h(ea[e0 * EDGEF + k]);
    if (t < 64) dids[t] = ei[NE + e0 + t];
    {
        int edge = t >> 1, i0 = (t & 1) * 8;
        int sid = ei[e0 + edge];
        f32x4 v0 = *(const f32x4*)&h[(long)sid * EMB + i0];
        f32x4 v1 = *(const f32x4*)&h[(long)sid * EMB + i0 + 4];
#pragma unroll
        for (int j = 0; j < 4; ++j) {
            hsst[(i0 + j) * 64 + edge]     = v0[j];
            hsst[(i0 + 4 + j) * 64 + edge] = v1[j];
        }
    }
    __syncthreads();   // the ONLY barrier: eas/dids/hsst read-only below

    const int wid = t >> 6, lane = t & 63, o = lane & 15, g = lane >> 4;
    u32* eb = &e12[wid * 2048];

    // ---- stage 1: A-frag from ea (k = g*8+j, real k<6) ----
    f16x8 a1[2];
#pragma unroll
    for (int m = 0; m < 2; ++m) {
        f16x8 a = {0, 0, 0, 0, 0, 0, 0, 0};
        if (g == 0) {
#pragma unroll
            for (int j = 0; j < EDGEF; ++j) {
                H16 v; v.u = eas[(wid * 32 + m * 16 + o) * EDGEF + j];
                a[j] = v.h;
            }
        }
        a1[m] = a;
    }
#pragma unroll
    for (int p = 0; p < 4; ++p) {
        f32x4 acc[2][2] = {};
#pragma unroll
        for (int nth = 0; nth < 2; ++nth) {
            B128 bb; bb.u = w1p[(p * 2 + nth) * 64 + lane];
#pragma unroll
            for (int m = 0; m < 2; ++m)
                acc[m][nth] = __builtin_amdgcn_mfma_f32_16x16x32_f16(a1[m], bb.h, acc[m][nth], 0, 0, 0);
        }
        float blo = b1[(p * 2) * 16 + o], bhi = b1[(p * 2 + 1) * 16 + o];
#pragma unroll
        for (int m = 0; m < 2; ++m)
#pragma unroll
            for (int r = 0; r < 4; ++r) {
                float lo = fmaxf(acc[m][0][r] + blo, 0.f);
                float hi = fmaxf(acc[m][1][r] + bhi, 0.f);
                int el = m * 16 + g * 4 + r;
                eb[(el * 64 + p * 16 + o) ^ ((el & 7) << 2)] =
                    (u32)f2h(lo) | ((u32)f2h(hi) << 16);
            }
    }
    // no barrier: eb is wave-private, DS ops in-order within a wave

    // ---- stage 2: e1 @ w2 ----
    f16x8 a2[2][4];
#pragma unroll
    for (int m = 0; m < 2; ++m) {
        int el = m * 16 + o;
#pragma unroll
        for (int ks = 0; ks < 4; ++ks) {
            B128 v; v.u = *(const uint4*)&eb[(el * 64 + ks * 16 + g * 4) ^ ((el & 7) << 2)];
            a2[m][ks] = v.h;
        }
    }
#pragma unroll
    for (int p = 0; p < 4; ++p) {
        f32x4 acc[2][2] = {};
#pragma unroll
        for (int ks = 0; ks < 4; ++ks)
#pragma unroll
            for (int nth = 0; nth < 2; ++nth) {
                B128 bb; bb.u = w2p[((p * 2 + nth) * 4 + ks) * 64 + lane];
#pragma unroll
                for (int m = 0; m < 2; ++m)
                    acc[m][nth] = __builtin_amdgcn_mfma_f32_16x16x32_f16(a2[m][ks], bb.h, acc[m][nth], 0, 0, 0);
            }
        float blo = b2[(p * 2) * 16 + o], bhi = b2[(p * 2 + 1) * 16 + o];
#pragma unroll
        for (int m = 0; m < 2; ++m)
#pragma unroll
            for (int r = 0; r < 4; ++r) {
                float lo = fmaxf(acc[m][0][r] + blo, 0.f);
                float hi = fmaxf(acc[m][1][r] + bhi, 0.f);
                int el = m * 16 + g * 4 + r;
                eb[(el * 64 + p * 16 + o) ^ ((el & 7) << 2)] =
                    (u32)f2h(lo) | ((u32)f2h(hi) << 16);
            }
    }

    // ---- stage 3: e2 @ w3, fold msg, scatter ----
    f16x8 a3[2][4];
#pragma unroll
    for (int m = 0; m < 2; ++m) {
        int el = m * 16 + o;
#pragma unroll
        for (int ks = 0; ks < 4; ++ks) {
            B128 v; v.u = *(const uint4*)&eb[(el * 64 + ks * 16 + g * 4) ^ ((el & 7) << 2)];
            a3[m][ks] = v.h;
        }
    }
    if (STORE_A3) {
        const long tb = ((long)blockIdx.x * 4 + wid * 2) * 4;   // tile*4ks base
#pragma unroll
        for (int m = 0; m < 2; ++m)
#pragma unroll
            for (int ks = 0; ks < 4; ++ks) {
                B128 v; v.h = a3[m][ks];
                a3c[(tb + m * 4 + ks) * 64 + lane] = v.u;
            }
    }
    f32x4 msg[2] = {};
#pragma unroll
    for (int ct = 0; ct < 16; ++ct) {
        f32x4 acc[2] = {};
#pragma unroll
        for (int ks = 0; ks < 4; ++ks) {
            B128 bb; bb.u = w3p[(ct * 4 + ks) * 64 + lane];
#pragma unroll
            for (int m = 0; m < 2; ++m)
                acc[m] = __builtin_amdgcn_mfma_f32_16x16x32_f16(a3[m][ks], bb.h, acc[m], 0, 0, 0);
        }
        float b3v = b3[ct * 16 + o];
#pragma unroll
        for (int m = 0; m < 2; ++m) {
            f32x4 hv = *(const f32x4*)&hsst[ct * 64 + wid * 32 + m * 16 + g * 4];
#pragma unroll
            for (int r = 0; r < 4; ++r)
                msg[m][r] += (acc[m][r] + b3v) * hv[r];
        }
    }
#pragma unroll
    for (int m = 0; m < 2; ++m)
#pragma unroll
        for (int r = 0; r < 4; ++r) {
            int elb = wid * 32 + m * 16 + g * 4 + r;
            atomicAdd(&agg[(long)dids[elb] * EMB + o], msg[m][r]);
        }
}

__global__ __launch_bounds__(128, 4) void gno_k(
    const int* __restrict__ ei, const float* __restrict__ ea,
    const uint4* __restrict__ w1p, const float* __restrict__ b1,
    const uint4* __restrict__ w2p, const float* __restrict__ b2,
    const uint4* __restrict__ w3p, const float* __restrict__ b3,
    const float* __restrict__ h, float* __restrict__ agg)
{
    gno_body<0>(ei, ea, w1p, b1, w2p, b2, w3p, b3, h, agg, nullptr);
}

__global__ __launch_bounds__(128, 4) void gno_store_k(
    const int* __restrict__ ei, const float* __restrict__ ea,
    const uint4* __restrict__ w1p, const float* __restrict__ b1,
    const uint4* __restrict__ w2p, const float* __restrict__ b2,
    const uint4* __restrict__ w3p, const float* __restrict__ b3,
    const float* __restrict__ h, float* __restrict__ agg,
    uint4* __restrict__ a3c)
{
    gno_body<1>(ei, ea, w1p, b1, w2p, b2, w3p, b3, h, agg, a3c);
}

// ---------------- reuse kernel: stage 3 only, a3 frags from cache ----------------
// R13: exact r11 shape (128 thr, 2 waves, 2 tiles/wave -- r12's 1-wave/4-tile
// traded TLP for ILP and regressed; reverted). a3c HBM loads issued FIRST so
// their ~900cy latency overlaps the dids/hsst gather + barrier.
__global__ __launch_bounds__(128, 6) void gno_reuse_k(
    const int* __restrict__ ei, const uint4* __restrict__ a3c,
    const uint4* __restrict__ w3p, const float* __restrict__ b3,
    const float* __restrict__ h, float* __restrict__ agg)
{
    __shared__ int   dids[64];
    __shared__ float hsst[16 * 64];

    const int t  = threadIdx.x;
    const long e0 = (long)blockIdx.x * 64;
    const int wid = t >> 6, lane = t & 63, o = lane & 15, g = lane >> 4;

    // prefetch a3 fragments (independent of LDS staging below)
    f16x8 a3[2][4];
    const long tb = ((long)blockIdx.x * 4 + wid * 2) * 4;
#pragma unroll
    for (int m = 0; m < 2; ++m)
#pragma unroll
        for (int ks = 0; ks < 4; ++ks) {
            B128 v; v.u = a3c[(tb + m * 4 + ks) * 64 + lane];
            a3[m][ks] = v.h;
        }

    if (t < 64) dids[t] = ei[NE + e0 + t];
    {
        int edge = t >> 1, i0 = (t & 1) * 8;
        int sid = ei[e0 + edge];
        f32x4 v0 = *(const f32x4*)&h[(long)sid * EMB + i0];
        f32x4 v1 = *(const f32x4*)&h[(long)sid * EMB + i0 + 4];
#pragma unroll
        for (int j = 0; j < 4; ++j) {
            hsst[(i0 + j) * 64 + edge]     = v0[j];
            hsst[(i0 + 4 + j) * 64 + edge] = v1[j];
        }
    }
    __syncthreads();

    f32x4 msg[2] = {};
#pragma unroll
    for (int ct = 0; ct < 16; ++ct) {
        f32x4 acc[2] = {};
#pragma unroll
        for (int ks = 0; ks < 4; ++ks) {
            B128 bb; bb.u = w3p[(ct * 4 + ks) * 64 + lane];
#pragma unroll
            for (int m = 0; m < 2; ++m)
                acc[m] = __builtin_amdgcn_mfma_f32_16x16x32_f16(a3[m][ks], bb.h, acc[m], 0, 0, 0);
        }
        float b3v = b3[ct * 16 + o];
#pragma unroll
        for (int m = 0; m < 2; ++m) {
            f32x4 hv = *(const f32x4*)&hsst[ct * 64 + wid * 32 + m * 16 + g * 4];
#pragma unroll
            for (int r = 0; r < 4; ++r)
                msg[m][r] += (acc[m][r] + b3v) * hv[r];
        }
    }
#pragma unroll
    for (int m = 0; m < 2; ++m)
#pragma unroll
        for (int r = 0; r < 4; ++r) {
            int elb = wid * 32 + m * 16 + g * 4 + r;
            atomicAdd(&agg[(long)dids[elb] * EMB + o], msg[m][r]);
        }
}

// ---------------- node update (also re-zeros agg for the next iteration) ----------------
__global__ void update_k(float* __restrict__ agg, const float* __restrict__ counts,
        const float* __restrict__ h, const float* __restrict__ rw,
        const float* __restrict__ cb, float* __restrict__ hn)
{
    int idx = blockIdx.x * blockDim.x + threadIdx.x;
    if (idx >= NN * EMB) return;
    int n = idx >> 4, o = idx & 15;
    float acc = cb[o];
#pragma unroll
    for (int i = 0; i < EMB; ++i) acc += h[n * EMB + i] * rw[i * EMB + o];
    float a = agg[idx] / fmaxf(counts[n], 1.0f);
    agg[idx] = 0.0f;   // zero for next conv iteration (saves a memset launch)
    hn[idx] = fmaxf(acc + a, 0.0f);
}

// ---------------- inverse embedding ----------------
__global__ void final_k(const float* __restrict__ h, const float* __restrict__ iw,
        const float* __restrict__ ib, float* __restrict__ out)
{
    int idx = blockIdx.x * blockDim.x + threadIdx.x;
    if (idx >= NN * INF) return;
    int n = idx / INF, f = idx % INF;
    float acc = ib[f];
#pragma unroll
    for (int i = 0; i < EMB; ++i) acc += h[n * EMB + i] * iw[i * INF + f];
    out[idx] = acc;
}

extern "C" void kernel_launch(void* const* d_in, const int* in_sizes, int n_in,
                              void* d_out, int out_size, void* d_ws, size_t ws_size,
                              hipStream_t stream)
{
    const float* x     = (const float*)d_in[0];
    const int*   ei    = (const int*)d_in[1];
    const float* ea    = (const float*)d_in[2];
    const float* emb_w = (const float*)d_in[3];
    const float* emb_b = (const float*)d_in[4];
    const float* k1w   = (const float*)d_in[5];
    const float* k1b   = (const float*)d_in[6];
    const float* k2w   = (const float*)d_in[7];
    const float* k2b   = (const float*)d_in[8];
    const float* k3w   = (const float*)d_in[9];
    const float* k3b   = (const float*)d_in[10];
    const float* rw    = (const float*)d_in[11];
    const float* cb    = (const float*)d_in[12];
    const float* iw    = (const float*)d_in[13];
    const float* ib    = (const float*)d_in[14];
    float* out = (float*)d_out;

    char* ws = (char*)d_ws;
    u16* w1p = (u16*)(ws);                    //  8 KB  (4096)
    u16* w2p = (u16*)(ws + 8192);             // 32 KB  (16384)
    u16* w3p = (u16*)(ws + 40960);            // 64 KB  (32768)
    size_t off = 106496;                      // 256B-aligned
    float* h0     = (float*)(ws + off); off += (size_t)NN * EMB * sizeof(float);
    float* h1     = (float*)(ws + off); off += (size_t)NN * EMB * sizeof(float);
    float* agg    = (float*)(ws + off); off += (size_t)NN * EMB * sizeof(float);
    float* counts = (float*)(ws + off); off += (size_t)NN * sizeof(float);

    // a3 fragment cache: 50000 tiles x 4 ks x 64 lanes x 16 B = 204.8 MB
    off = (off + 255) & ~(size_t)255;
    uint4* a3c = (uint4*)(ws + off);
    const size_t A3_BYTES = (size_t)(NE / 16) * 4 * 64 * 16;
    const bool cacheA3 = (ws_size >= off + A3_BYTES);

    hipMemsetAsync(counts, 0, (size_t)NN * sizeof(float), stream);
    hipMemsetAsync(agg, 0, (size_t)NN * EMB * sizeof(float), stream);
    prep_k<<<208, 256, 0, stream>>>(k1w, k2w, k3w, w1p, w2p, w3p);
    embed_k<<<(NN * EMB + 255) / 256, 256, 0, stream>>>(x, emb_w, emb_b, h0);
    count_k<<<(NE + 255) / 256, 256, 0, stream>>>(ei + NE, counts);

    float* hc = h0;
    float* hn = h1;
    for (int it = 0; it < NCONV; ++it) {
        // agg zeroed by initial memset (it==0) or by update_k of the previous iter
        if (!cacheA3) {
            gno_k<<<NE / 64, 128, 0, stream>>>(ei, ea,
                    (const uint4*)w1p, k1b, (const uint4*)w2p, k2b,
                    (const uint4*)w3p, k3b, hc, agg);
        } else if (it == 0) {
            gno_store_k<<<NE / 64, 128, 0, stream>>>(ei, ea,
                    (const uint4*)w1p, k1b, (const uint4*)w2p, k2b,
                    (const uint4*)w3p, k3b, hc, agg, a3c);
        } else {
            gno_reuse_k<<<NE / 64, 128, 0, stream>>>(ei, a3c,
                    (const uint4*)w3p, k3b, hc, agg);
        }
        update_k<<<(NN * EMB + 255) / 256, 256, 0, stream>>>(agg, counts, hc, rw, cb, hn);
        float* tmp = hc; hc = hn; hn = tmp;
    }
    final_k<<<(NN * INF + 255) / 256, 256, 0, stream>>>(hc, iw, ib, out);
}